// Round 14
// baseline (348.066 us; speedup 1.0000x reference)
//
#include <hip/hip_runtime.h>

// ---------------------------------------------------------------------------
// Round 14: NFRAG=8 convs (wave = 64 oc x 128 px) to halve A-bytes/MFMA
// (L1 weight-bandwidth was the measured 28%-MfmaUtil ceiling in R10-R13).
// Fused 2x2 maxpool now fully in REGISTERS via shfl_xor (no LDS scratch,
// no epilogue barriers). K-loop = R10 form (ternary A-prefetch).
// NC8HW8 bf16 activations, linear frag-order weights, fp32 in / fp32 out.
// ---------------------------------------------------------------------------

typedef __attribute__((ext_vector_type(8))) short short8;
typedef __attribute__((ext_vector_type(4))) float floatx4;
typedef unsigned int uint;
typedef unsigned short ushort;

__device__ __forceinline__ ushort f2bf(float f) {
    uint u = __float_as_uint(f);
    return (ushort)((u + 0x7fffu + ((u >> 16) & 1u)) >> 16);
}
__device__ __forceinline__ float bf2f(ushort h) {
    return __uint_as_float(((uint)h) << 16);
}

// ---------------- merged weight transform ----------------
__device__ __forceinline__ void wt_lin_one(
    const float* __restrict__ src, short* __restrict__ dst, int OC, int IC, int o)
{
    int j    = o & 7;
    int lane = (o >> 3) & 63;
    int r    = o >> 9;
    int G16  = OC >> 4;
    int g    = r % G16;  r /= G16;
    int kk   = r % 9;
    int icb  = r / 9;
    int oc = g * 16 + (lane & 15);
    int ic = icb * 32 + (lane >> 4) * 8 + j;
    dst[o] = (short)f2bf(src[((long)oc * IC + ic) * 9 + kk]);
}

__global__ __launch_bounds__(256) void wtransform_all(
    const float* __restrict__ w0, const float* __restrict__ w1,
    const float* __restrict__ w2, const float* __restrict__ w3,
    const float* __restrict__ w4, const float* __restrict__ w5,
    short* __restrict__ dst0, short* __restrict__ dst1, short* __restrict__ dst2,
    short* __restrict__ dst3, short* __restrict__ dst4, short* __restrict__ dst5)
{
    int o = blockIdx.x * 256 + threadIdx.x;
    if (o < 2048) {                                   // conv0
        int oc = o >> 5, k = o & 31;
        dst0[o] = (k < 27) ? (short)f2bf(w0[oc * 27 + k]) : (short)0;
        return;
    }
    o -= 2048;
    if (o < 36864)  { wt_lin_one(w1, dst1,  64,  64, o); return; }
    o -= 36864;
    if (o < 73728)  { wt_lin_one(w2, dst2, 128,  64, o); return; }
    o -= 73728;
    if (o < 147456) { wt_lin_one(w3, dst3, 128, 128, o); return; }
    o -= 147456;
    if (o < 294912) { wt_lin_one(w4, dst4, 256, 128, o); return; }
    o -= 294912;
    if (o < 589824) { wt_lin_one(w5, dst5, 256, 256, o); return; }
}

// ---------------- conv0 MFMA: 3->64 @32x32, NCHW fp32 in, NC8HW8 bf16 out
__global__ __launch_bounds__(256, 2) void conv0_mfma(
    const float* __restrict__ x, const short* __restrict__ wT0,
    const float* __restrict__ b0, ushort* __restrict__ out)
{
    __shared__ float  s_x[3 * 18 * 34];
    __shared__ ushort s_b[4 * 512 * 8];

    const int tid  = threadIdx.x;
    const int wv   = tid >> 6;
    const int lane = tid & 63;
    const int quad = lane >> 4;
    const int l16  = lane & 15;
    const int b    = blockIdx.x >> 1;
    const int r0   = (blockIdx.x & 1) * 16;

    for (int idx = tid; idx < 3 * 18 * 34; idx += 256) {
        int c   = idx / 612;
        int rem = idx - c * 612;
        int ry  = rem / 34, rx = rem - ry * 34;
        int gy  = r0 + ry - 1, gx = rx - 1;
        float v = 0.f;
        if (gy >= 0 && gy < 32 && gx >= 0 && gx < 32)
            v = x[(((long)b * 3 + c) * 32 + gy) * 32 + gx];
        s_x[idx] = v;
    }
    __syncthreads();

#pragma unroll
    for (int rep = 0; rep < 2; ++rep) {
        int pxl = rep * 256 + tid;
        int py = pxl >> 5, px = pxl & 31;
        ushort v[32];
#pragma unroll
        for (int c = 0; c < 3; ++c)
#pragma unroll
            for (int ky = 0; ky < 3; ++ky)
#pragma unroll
                for (int kx = 0; kx < 3; ++kx)
                    v[c * 9 + ky * 3 + kx] = f2bf(s_x[c * 612 + (py + ky) * 34 + (px + kx)]);
#pragma unroll
        for (int k = 27; k < 32; ++k) v[k] = 0;
#pragma unroll
        for (int q = 0; q < 4; ++q)
            *(uint4*)(&s_b[(q * 512 + pxl) * 8]) = *(const uint4*)(v + q * 8);
    }
    __syncthreads();

    floatx4 acc[4][8];
#pragma unroll
    for (int i = 0; i < 4; ++i)
#pragma unroll
        for (int t = 0; t < 8; ++t) acc[i][t] = (floatx4)0.f;

    short8 afr[4];
#pragma unroll
    for (int i = 0; i < 4; ++i)
        afr[i] = *(const short8*)(wT0 + (i * 16 + l16) * 32 + quad * 8);
#pragma unroll
    for (int t = 0; t < 8; ++t) {
        int pxl = wv * 128 + t * 16 + l16;
        short8 bfr = *(const short8*)(&s_b[(quad * 512 + pxl) * 8]);
#pragma unroll
        for (int i = 0; i < 4; ++i)
            acc[i][t] = __builtin_amdgcn_mfma_f32_16x16x32_bf16(afr[i], bfr, acc[i][t], 0, 0, 0);
    }

#pragma unroll
    for (int i = 0; i < 4; ++i) {
        int oc0 = i * 16 + quad * 4;
        float4 bv = *(const float4*)(b0 + oc0);
#pragma unroll
        for (int t = 0; t < 8; ++t) {
            int pxl = wv * 128 + t * 16 + l16;
            int py = pxl >> 5, px = pxl & 31;
            long dst = ((((long)b * 8 + (oc0 >> 3)) * 32 + r0 + py) * 32 + px) * 8 + (oc0 & 7);
            float v0 = acc[i][t][0] + bv.x;
            float v1 = acc[i][t][1] + bv.y;
            float v2 = acc[i][t][2] + bv.z;
            float v3 = acc[i][t][3] + bv.w;
            ushort o[4];
            o[0] = f2bf(v0 > 0.f ? v0 : 0.f);
            o[1] = f2bf(v1 > 0.f ? v1 : 0.f);
            o[2] = f2bf(v2 > 0.f ? v2 : 0.f);
            o[3] = f2bf(v3 > 0.f ? v3 : 0.f);
            *(uint2*)(out + dst) = *(uint2*)o;
        }
    }
}

__device__ __forceinline__ floatx4 relu_bias(floatx4 a, float4 bv) {
    floatx4 r;
    r[0] = a[0] + bv.x; r[1] = a[1] + bv.y; r[2] = a[2] + bv.z; r[3] = a[3] + bv.w;
#pragma unroll
    for (int j = 0; j < 4; ++j) r[j] = r[j] > 0.f ? r[j] : 0.f;
    return r;
}
__device__ __forceinline__ floatx4 max_xor(floatx4 v, int m) {
    floatx4 r;
#pragma unroll
    for (int j = 0; j < 4; ++j) {
        float o = __shfl_xor(v[j], m, 64);
        r[j] = v[j] > o ? v[j] : o;
    }
    return r;
}
__device__ __forceinline__ floatx4 max4(floatx4 a, floatx4 b) {
    floatx4 r;
#pragma unroll
    for (int j = 0; j < 4; ++j) r[j] = a[j] > b[j] ? a[j] : b[j];
    return r;
}
__device__ __forceinline__ void store_bf4(ushort* p, floatx4 v) {
    ushort o[4];
#pragma unroll
    for (int j = 0; j < 4; ++j) o[j] = f2bf(v[j]);
    *(uint2*)p = *(uint2*)o;
}

// ---------------- NFRAG=8 conv3x3+ReLU (+register-pooled 2x2 max)
// Block = 4 waves = OCGROUPS x PXG. Wave = 64 oc x 128 px. NSAMP samples/block.
template<int IC, int OC, int H, int W, int ROWS, int OCGROUPS, int OCSPLIT,
         int NSAMP, int NSTAGE, bool POOL>
__global__ __launch_bounds__(256, 2) void conv_nf8(
    const ushort* __restrict__ act_in,  // [B][IC/8][H][W][8]
    const short*  __restrict__ wTs,     // linear frag-order bf16
    const float*  __restrict__ bias,
    ushort* __restrict__ act_out)       // [B][OC/8][H'][W'][8]
{
    constexpr int PXG   = 4 / OCGROUPS;
    constexpr int WPAD  = W + 2;
    constexpr int RPAD  = ROWS + 2;
    constexpr int SUNIT = RPAD * WPAD;
    constexpr int UNITS = NSAMP * SUNIT;
    constexpr int SEGS  = H / ROWS;
    constexpr int C8I   = IC / 8;
    constexpr int C8H   = C8I / NSTAGE;
    constexpr int CPUP  = C8H + 1;
    constexpr int G16   = OC / 16;
    constexpr int NICBH = (IC / 32) / NSTAGE;
    constexpr int C8O   = OC / 8;
    constexpr int TMAX  = (IC / 32) * 9;
    static_assert(PXG * 128 == NSAMP * ROWS * W, "px tiling mismatch");
    static_assert(!POOL || W != 8 || PXG == 1, "W=8 pool needs PXG=1");

    __shared__ ushort s_act[UNITS * CPUP * 8];

    const int tid  = threadIdx.x;
    const int wv   = tid >> 6;
    const int lane = tid & 63;
    const int quad = lane >> 4;
    const int l16  = lane & 15;

    int bx = blockIdx.x;
    const int ocb = bx % OCSPLIT;  bx /= OCSPLIT;
    const int seg = bx % SEGS;
    const int b0  = (bx / SEGS) * NSAMP;
    const int r0  = seg * ROWS;
    const int ocg = wv % OCGROUPS;
    const int pxg = wv / OCGROUPS;
    const int gbase = (ocb * OCGROUPS + ocg) * 4;

    floatx4 acc[4][8];
#pragma unroll
    for (int i = 0; i < 4; ++i)
#pragma unroll
        for (int t = 0; t < 8; ++t) acc[i][t] = (floatx4)0.f;

    int bbase[8];
#pragma unroll
    for (int t = 0; t < 8; ++t) {
        int pxl = pxg * 128 + t * 16 + l16;
        int s   = pxl / (ROWS * W);
        int p2  = pxl - s * (ROWS * W);
        int py  = p2 / W, px = p2 - py * W;
        bbase[t] = (s * SUNIT + py * WPAD + px) * CPUP * 8;
    }

    const short8* wb = (const short8*)wTs;
    short8 afr[4];
#pragma unroll
    for (int i = 0; i < 4; ++i)
        afr[i] = wb[((long)0 * G16 + gbase + i) * 64 + lane];

    int tl = 0;
    for (int st = 0; st < NSTAGE; ++st) {
        if (st) __syncthreads();
        for (int c = tid; c < UNITS * C8H; c += 256) {
            int sub  = c / UNITS;
            int unit = c - sub * UNITS;
            int s    = unit / SUNIT;
            int rem  = unit - s * SUNIT;
            int ry   = rem / WPAD, cx = rem - ry * WPAD;
            int gy   = r0 + ry - 1, gx = cx - 1;
            uint4 val = make_uint4(0, 0, 0, 0);
            if ((unsigned)gy < (unsigned)H && (unsigned)gx < (unsigned)W) {
                long src = ((((long)(b0 + s) * C8I + st * C8H + sub) * H + gy) * W + gx) * 8;
                val = *(const uint4*)(act_in + src);
            }
            *(uint4*)(&s_act[((size_t)unit * CPUP + sub) * 8]) = val;
        }
        __syncthreads();

        for (int icb = 0; icb < NICBH; ++icb) {
#pragma unroll
            for (int kk = 0; kk < 9; ++kk) {
                const int ky = kk / 3, kx = kk - ky * 3;
                const int koff = ((ky * WPAD + kx) * CPUP + icb * 4 + quad) * 8;
                short8 bfr[8];
#pragma unroll
                for (int t = 0; t < 8; ++t)
                    bfr[t] = *(const short8*)(&s_act[bbase[t] + koff]);
                int tn = (tl + 1 < TMAX) ? tl + 1 : tl;
                short8 afrN[4];
#pragma unroll
                for (int i = 0; i < 4; ++i)
                    afrN[i] = wb[((long)tn * G16 + gbase + i) * 64 + lane];
#pragma unroll
                for (int i = 0; i < 4; ++i)
#pragma unroll
                    for (int t = 0; t < 8; ++t)
                        acc[i][t] = __builtin_amdgcn_mfma_f32_16x16x32_bf16(
                            afr[i], bfr[t], acc[i][t], 0, 0, 0);
#pragma unroll
                for (int i = 0; i < 4; ++i) afr[i] = afrN[i];
                ++tl;
            }
        }
    }

#pragma unroll
    for (int i = 0; i < 4; ++i) {
        const int oc0 = (gbase + i) * 16 + quad * 4;
        const float4 bv = *(const float4*)(bias + oc0);
        if constexpr (!POOL) {
#pragma unroll
            for (int t = 0; t < 8; ++t) {
                int pxl = pxg * 128 + t * 16 + l16;
                int s   = pxl / (ROWS * W);
                int p2  = pxl - s * (ROWS * W);
                int py  = p2 / W, px = p2 - py * W;
                long dst = ((((long)(b0 + s) * C8O + (oc0 >> 3)) * H + r0 + py) * W + px) * 8 + (oc0 & 7);
                store_bf4(act_out + dst, relu_bias(acc[i][t], bv));
            }
        } else {
            floatx4 r[8];
#pragma unroll
            for (int t = 0; t < 8; ++t)
                r[t] = max_xor(relu_bias(acc[i][t], bv), 1);   // x-pair
            if constexpr (W == 16) {
                // frag t = row (pxg*8 + t); y-pair = (2tp, 2tp+1)
                constexpr int HO = H / 2, WO = W / 2;
#pragma unroll
                for (int tp = 0; tp < 4; ++tp) {
                    floatx4 m = max4(r[2 * tp], r[2 * tp + 1]);
                    if ((l16 & 1) == 0) {
                        int prow = pxg * 4 + tp;
                        int pcol = l16 >> 1;
                        long dst = ((((long)b0 * C8O + (oc0 >> 3)) * HO + prow) * WO + pcol) * 8 + (oc0 & 7);
                        store_bf4(act_out + dst, m);
                    }
                }
            } else if constexpr (W == 32) {
                // frag t: row = pxg*4 + (t>>1), halfcol = t&1; y-pair (t, t+2)
                constexpr int HO = H / 2, WO = W / 2;
#pragma unroll
                for (int j = 0; j < 2; ++j)
#pragma unroll
                    for (int k = 0; k < 2; ++k) {
                        floatx4 m = max4(r[j * 4 + k], r[j * 4 + k + 2]);
                        if ((l16 & 1) == 0) {
                            int prow = r0 / 2 + pxg * 2 + j;
                            int pcol = k * 8 + (l16 >> 1);
                            long dst = ((((long)b0 * C8O + (oc0 >> 3)) * HO + prow) * WO + pcol) * 8 + (oc0 & 7);
                            store_bf4(act_out + dst, m);
                        }
                    }
            } else {  // W == 8, PXG==1, NSAMP samples: frag t -> sample t>>2
                constexpr int HO = H / 2, WO = W / 2;
#pragma unroll
                for (int t = 0; t < 8; ++t) {
                    floatx4 m = max_xor(r[t], 8);              // y-pair
                    if ((l16 & 1) == 0 && l16 < 8) {
                        int bb   = b0 + (t >> 2);
                        int prow = t & 3;
                        int pcol = l16 >> 1;
                        long dst = ((((long)bb * C8O + (oc0 >> 3)) * HO + prow) * WO + pcol) * 8 + (oc0 & 7);
                        store_bf4(act_out + dst, m);
                    }
                }
            }
        }
    }
}

// ---------------- classifier: wave per (b, class); feat [b][c8][y][x][8]
__global__ __launch_bounds__(256) void classifier_k(
    const ushort* __restrict__ feat, const int* __restrict__ tids,
    const float* __restrict__ cw, const float* __restrict__ cb,
    float* __restrict__ out, int B)
{
    int g = blockIdx.x * 256 + threadIdx.x;
    int wid = g >> 6, lane = g & 63;
    if (wid >= B * 5) return;
    int b = wid / 5, c = wid - b * 5;
    int t = tids[b];
    const float* wrow = cw + (long)(t * 5 + c) * 4096;
    const ushort* f = feat + (long)b * 4096;
    float s = 0.f;
#pragma unroll 4
    for (int d = lane; d < 4096; d += 64) {
        int fidx = (((d >> 7) * 16) + (d & 15)) * 8 + ((d >> 4) & 7);
        s += wrow[d] * bf2f(f[fidx]);
    }
#pragma unroll
    for (int off = 32; off > 0; off >>= 1) s += __shfl_down(s, off, 64);
    if (lane == 0) out[wid] = s + cb[t * 5 + c];
}

// ---------------------------------------------------------------------------
extern "C" void kernel_launch(void* const* d_in, const int* in_sizes, int n_in,
                              void* d_out, int out_size, void* d_ws, size_t ws_size,
                              hipStream_t stream)
{
    const float* x   = (const float*)d_in[0];
    const int*   tid = (const int*)d_in[1];
    const float* w0 = (const float*)d_in[2];  const float* b0 = (const float*)d_in[3];
    const float* w1 = (const float*)d_in[4];  const float* b1 = (const float*)d_in[5];
    const float* w2 = (const float*)d_in[6];  const float* b2 = (const float*)d_in[7];
    const float* w3 = (const float*)d_in[8];  const float* b3 = (const float*)d_in[9];
    const float* w4 = (const float*)d_in[10]; const float* b4 = (const float*)d_in[11];
    const float* w5 = (const float*)d_in[12]; const float* b5 = (const float*)d_in[13];
    const float* cw = (const float*)d_in[14];
    const float* cb = (const float*)d_in[15];
    float* outp = (float*)d_out;

    const int B = in_sizes[0] / (3 * 32 * 32);   // 512

    // ---- ws layout (halfword units) ----
    short* wt0  = (short*)d_ws;                   // 2048
    short* wts1 = wt0 + 2048;                     // 36864
    short* wts2 = wts1 + 36864;                   // 73728
    short* wts3 = wts2 + 73728;                   // 147456
    short* wts4 = wts3 + 147456;                  // 294912
    short* wts5 = wts4 + 294912;                  // 589824
    const size_t WT_HW = 2048 + 36864 + 73728 + 147456 + 294912 + 589824;
    const size_t fixed_bytes = WT_HW * 2;

    int Bc = B;
    while (Bc > 2 && fixed_bytes + (size_t)Bc * 2 * 65536 * 2 > ws_size) Bc >>= 1;
    if (Bc < 2) Bc = 2;

    ushort* bufA = (ushort*)((short*)d_ws + WT_HW);
    ushort* bufB = bufA + (size_t)Bc * 65536;

    wtransform_all<<<(int)((WT_HW + 255) / 256), 256, 0, stream>>>(
        w0, w1, w2, w3, w4, w5, wt0, wts1, wts2, wts3, wts4, wts5);

    for (int cb0 = 0; cb0 < B; cb0 += Bc) {
        const float* xc = x + (size_t)cb0 * 3 * 32 * 32;
        const int* tidc = tid + cb0;
        float* outc = outp + (size_t)cb0 * 5;

        // conv0: 3->64 @32x32 -> bufA [Bc][8][32][32][8]
        conv0_mfma<<<Bc * 2, 256, 0, stream>>>(xc, wt0, b0, bufA);
        // conv1+pool: 64->64 @32x32 (OCG=1, ROWS=16, NSTAGE=2) -> bufB 16x16
        conv_nf8<64, 64, 32, 32, 16, 1, 1, 1, 2, true><<<Bc * 2, 256, 0, stream>>>(bufA, wts1, b1, bufB);
        // conv2: 64->128 @16x16 (OCG=2, full image) -> bufA
        conv_nf8<64, 128, 16, 16, 16, 2, 1, 1, 1, false><<<Bc, 256, 0, stream>>>(bufB, wts2, b2, bufA);
        // conv3+pool: 128->128 @16x16 (OCG=2, NSTAGE=2) -> bufB 8x8
        conv_nf8<128, 128, 16, 16, 16, 2, 1, 1, 2, true><<<Bc, 256, 0, stream>>>(bufA, wts3, b3, bufB);
        // conv4: 128->256 @8x8 (OCG=4, NSAMP=2, NSTAGE=2) -> bufA
        conv_nf8<128, 256, 8, 8, 8, 4, 1, 2, 2, false><<<Bc / 2, 256, 0, stream>>>(bufB, wts4, b4, bufA);
        // conv5+pool: 256->256 @8x8 (OCG=4, NSAMP=2, NSTAGE=2) -> bufB 4x4
        conv_nf8<256, 256, 8, 8, 8, 4, 1, 2, 2, true><<<Bc / 2, 256, 0, stream>>>(bufA, wts5, b5, bufB);
        // classifier
        classifier_k<<<(Bc * 5 * 64 + 255) / 256, 256, 0, stream>>>(bufB, tidc, cw, cb, outc, Bc);
    }
}

// Round 15
// 341.744 us; speedup vs baseline: 1.0185x; 1.0185x over previous
//
#include <hip/hip_runtime.h>

// ---------------------------------------------------------------------------
// Round 15: 32x32x16 MFMA convs (half the MFMA instruction count per FLOP —
// R10-R14 plateau diagnosed as SIMD issue-slot saturation) + no manual A
// rotation. Wave = 64 oc x 64 px = 2x2 frags of 32x32. Register-space 2x2
// maxpool epilogues (shfl_xor). NC8HW8 bf16 acts, fp32 in/out.
// C/D: col=lane&31, row=(reg&3)+8*(reg>>2)+4*(lane>>5)  [m74/m101 verified]
// A/B: m|n = lane&31, k = (lane>>5)*8 + j.
// ---------------------------------------------------------------------------

typedef __attribute__((ext_vector_type(8)))  short short8;
typedef __attribute__((ext_vector_type(4)))  float floatx4;
typedef __attribute__((ext_vector_type(16))) float floatx16;
typedef unsigned int uint;
typedef unsigned short ushort;

__device__ __forceinline__ ushort f2bf(float f) {
    uint u = __float_as_uint(f);
    return (ushort)((u + 0x7fffu + ((u >> 16) & 1u)) >> 16);
}
__device__ __forceinline__ float bf2f(ushort h) {
    return __uint_as_float(((uint)h) << 16);
}

// ---------------- weight transforms ----------------
// conv1-5 (32-frag linear order): dst[((s*G32+g)*64+lane)*8+j],
//   s = ic16*9+kk, oc = g*32+(lane&31), ic = ic16*16+(lane>>5)*8+j
__device__ __forceinline__ void wt32_one(
    const float* __restrict__ src, short* __restrict__ dst, int OC, int IC, int o)
{
    int j    = o & 7;
    int lane = (o >> 3) & 63;
    int r    = o >> 9;
    int G32  = OC >> 5;
    int g    = r % G32;
    int s    = r / G32;
    int kk   = s % 9;
    int ic16 = s / 9;
    int oc = g * 32 + (lane & 31);
    int ic = ic16 * 16 + (lane >> 5) * 8 + j;
    dst[o] = (short)f2bf(src[((long)oc * IC + ic) * 9 + kk]);
}

__global__ __launch_bounds__(256) void wtransform_all(
    const float* __restrict__ w0, const float* __restrict__ w1,
    const float* __restrict__ w2, const float* __restrict__ w3,
    const float* __restrict__ w4, const float* __restrict__ w5,
    short* __restrict__ dst0, short* __restrict__ dst1, short* __restrict__ dst2,
    short* __restrict__ dst3, short* __restrict__ dst4, short* __restrict__ dst5)
{
    int o = blockIdx.x * 256 + threadIdx.x;
    if (o < 2048) {                                   // conv0 (16x16x32 path)
        int oc = o >> 5, k = o & 31;
        dst0[o] = (k < 27) ? (short)f2bf(w0[oc * 27 + k]) : (short)0;
        return;
    }
    o -= 2048;
    if (o < 36864)  { wt32_one(w1, dst1,  64,  64, o); return; }
    o -= 36864;
    if (o < 73728)  { wt32_one(w2, dst2, 128,  64, o); return; }
    o -= 73728;
    if (o < 147456) { wt32_one(w3, dst3, 128, 128, o); return; }
    o -= 147456;
    if (o < 294912) { wt32_one(w4, dst4, 256, 128, o); return; }
    o -= 294912;
    if (o < 589824) { wt32_one(w5, dst5, 256, 256, o); return; }
}

// ---------------- conv0 MFMA (16x16x32): 3->64 @32x32, fp32 NCHW -> NC8HW8 bf16
__global__ __launch_bounds__(256, 2) void conv0_mfma(
    const float* __restrict__ x, const short* __restrict__ wT0,
    const float* __restrict__ b0, ushort* __restrict__ out)
{
    __shared__ float  s_x[3 * 18 * 34];
    __shared__ ushort s_b[4 * 512 * 8];

    const int tid  = threadIdx.x;
    const int wv   = tid >> 6;
    const int lane = tid & 63;
    const int quad = lane >> 4;
    const int l16  = lane & 15;
    const int b    = blockIdx.x >> 1;
    const int r0   = (blockIdx.x & 1) * 16;

    for (int idx = tid; idx < 3 * 18 * 34; idx += 256) {
        int c   = idx / 612;
        int rem = idx - c * 612;
        int ry  = rem / 34, rx = rem - ry * 34;
        int gy  = r0 + ry - 1, gx = rx - 1;
        float v = 0.f;
        if (gy >= 0 && gy < 32 && gx >= 0 && gx < 32)
            v = x[(((long)b * 3 + c) * 32 + gy) * 32 + gx];
        s_x[idx] = v;
    }
    __syncthreads();

#pragma unroll
    for (int rep = 0; rep < 2; ++rep) {
        int pxl = rep * 256 + tid;
        int py = pxl >> 5, px = pxl & 31;
        ushort v[32];
#pragma unroll
        for (int c = 0; c < 3; ++c)
#pragma unroll
            for (int ky = 0; ky < 3; ++ky)
#pragma unroll
                for (int kx = 0; kx < 3; ++kx)
                    v[c * 9 + ky * 3 + kx] = f2bf(s_x[c * 612 + (py + ky) * 34 + (px + kx)]);
#pragma unroll
        for (int k = 27; k < 32; ++k) v[k] = 0;
#pragma unroll
        for (int q = 0; q < 4; ++q)
            *(uint4*)(&s_b[(q * 512 + pxl) * 8]) = *(const uint4*)(v + q * 8);
    }
    __syncthreads();

    floatx4 acc[4][8];
#pragma unroll
    for (int i = 0; i < 4; ++i)
#pragma unroll
        for (int t = 0; t < 8; ++t) acc[i][t] = (floatx4)0.f;

    short8 afr[4];
#pragma unroll
    for (int i = 0; i < 4; ++i)
        afr[i] = *(const short8*)(wT0 + (i * 16 + l16) * 32 + quad * 8);
#pragma unroll
    for (int t = 0; t < 8; ++t) {
        int pxl = wv * 128 + t * 16 + l16;
        short8 bfr = *(const short8*)(&s_b[(quad * 512 + pxl) * 8]);
#pragma unroll
        for (int i = 0; i < 4; ++i)
            acc[i][t] = __builtin_amdgcn_mfma_f32_16x16x32_bf16(afr[i], bfr, acc[i][t], 0, 0, 0);
    }

#pragma unroll
    for (int i = 0; i < 4; ++i) {
        int oc0 = i * 16 + quad * 4;
        float4 bv = *(const float4*)(b0 + oc0);
#pragma unroll
        for (int t = 0; t < 8; ++t) {
            int pxl = wv * 128 + t * 16 + l16;
            int py = pxl >> 5, px = pxl & 31;
            long dst = ((((long)b * 8 + (oc0 >> 3)) * 32 + r0 + py) * 32 + px) * 8 + (oc0 & 7);
            float v0 = acc[i][t][0] + bv.x;
            float v1 = acc[i][t][1] + bv.y;
            float v2 = acc[i][t][2] + bv.z;
            float v3 = acc[i][t][3] + bv.w;
            ushort o[4];
            o[0] = f2bf(v0 > 0.f ? v0 : 0.f);
            o[1] = f2bf(v1 > 0.f ? v1 : 0.f);
            o[2] = f2bf(v2 > 0.f ? v2 : 0.f);
            o[3] = f2bf(v3 > 0.f ? v3 : 0.f);
            *(uint2*)(out + dst) = *(uint2*)o;
        }
    }
}

__device__ __forceinline__ floatx4 max_xor(floatx4 v, int m) {
    floatx4 r;
#pragma unroll
    for (int j = 0; j < 4; ++j) {
        float o = __shfl_xor(v[j], m, 64);
        r[j] = v[j] > o ? v[j] : o;
    }
    return r;
}
__device__ __forceinline__ floatx4 max4(floatx4 a, floatx4 b) {
    floatx4 r;
#pragma unroll
    for (int j = 0; j < 4; ++j) r[j] = a[j] > b[j] ? a[j] : b[j];
    return r;
}
__device__ __forceinline__ void store_bf4(ushort* p, floatx4 v) {
    ushort o[4];
#pragma unroll
    for (int j = 0; j < 4; ++j) o[j] = f2bf(v[j]);
    *(uint2*)p = *(uint2*)o;
}

// ---------------- 32x32x16 conv3x3+ReLU (+register-pooled 2x2 max)
// Block = 4 waves = OCGROUPS x PXG. Wave = 64 oc x 64 px (2x2 32-frags).
template<int IC, int OC, int H, int W, int ROWS, int OCGROUPS, int NSTAGE, bool POOL>
__global__ __launch_bounds__(256, 2) void conv32(
    const ushort* __restrict__ act_in,  // [B][IC/8][H][W][8]
    const short*  __restrict__ wTs,     // 32-frag linear order bf16
    const float*  __restrict__ bias,
    ushort* __restrict__ act_out)       // [B][OC/8][H'][W'][8]
{
    constexpr int PXG    = 4 / OCGROUPS;
    constexpr int WPAD   = W + 2;
    constexpr int RPAD   = ROWS + 2;
    constexpr int UNITS  = RPAD * WPAD;
    constexpr int SEGS   = H / ROWS;
    constexpr int C8I    = IC / 8;
    constexpr int C8H    = C8I / NSTAGE;
    constexpr int CPUP   = C8H + 1;
    constexpr int G32    = OC / 32;
    constexpr int NIC16H = (IC / 16) / NSTAGE;
    constexpr int C8O    = OC / 8;
    static_assert(PXG * 64 == ROWS * W, "px tiling mismatch");

    __shared__ ushort s_act[UNITS * CPUP * 8];

    const int tid  = threadIdx.x;
    const int wv   = tid >> 6;
    const int lane = tid & 63;
    const int l31  = lane & 31;
    const int half = lane >> 5;

    const int b   = blockIdx.x / SEGS;
    const int seg = blockIdx.x - b * SEGS;
    const int r0  = seg * ROWS;
    const int ocg = wv % OCGROUPS;
    const int pxg = wv / OCGROUPS;
    const int gb  = ocg * 2;            // two g32 groups per wave (64 oc)

    floatx16 acc[2][2];
#pragma unroll
    for (int a = 0; a < 2; ++a)
#pragma unroll
        for (int f = 0; f < 2; ++f)
#pragma unroll
            for (int r = 0; r < 16; ++r) acc[a][f][r] = 0.f;

    int bbase[2];
#pragma unroll
    for (int f = 0; f < 2; ++f) {
        int px = pxg * 64 + f * 32 + l31;
        int y  = px / W, xx = px - y * W;
        bbase[f] = ((y * WPAD + xx) * CPUP + half) * 8;
    }

    const short8* wb = (const short8*)wTs;

    for (int st = 0; st < NSTAGE; ++st) {
        if (st) __syncthreads();
        for (int c = tid; c < UNITS * C8H; c += 256) {
            int sub  = c / UNITS;
            int unit = c - sub * UNITS;
            int ry   = unit / WPAD, cx = unit - ry * WPAD;
            int gy   = r0 + ry - 1, gx = cx - 1;
            uint4 val = make_uint4(0, 0, 0, 0);
            if ((unsigned)gy < (unsigned)H && (unsigned)gx < (unsigned)W) {
                long src = ((((long)b * C8I + st * C8H + sub) * H + gy) * W + gx) * 8;
                val = *(const uint4*)(act_in + src);
            }
            *(uint4*)(&s_act[((size_t)unit * CPUP + sub) * 8]) = val;
        }
        __syncthreads();

        for (int ic16 = 0; ic16 < NIC16H; ++ic16) {
#pragma unroll
            for (int kk = 0; kk < 9; ++kk) {
                const int ky = kk / 3, kx = kk - ky * 3;
                const int koff = (ky * WPAD + kx) * CPUP * 8 + ic16 * 16;
                short8 bfr[2];
#pragma unroll
                for (int f = 0; f < 2; ++f)
                    bfr[f] = *(const short8*)(&s_act[bbase[f] + koff]);
                const int s = (st * NIC16H + ic16) * 9 + kk;
                short8 afr[2];
#pragma unroll
                for (int a = 0; a < 2; ++a)
                    afr[a] = wb[((long)s * G32 + gb + a) * 64 + lane];
#pragma unroll
                for (int a = 0; a < 2; ++a)
#pragma unroll
                    for (int f = 0; f < 2; ++f)
                        acc[a][f] = __builtin_amdgcn_mfma_f32_32x32x16_bf16(
                            afr[a], bfr[f], acc[a][f], 0, 0, 0);
            }
        }
    }

    // ---- epilogue: oc = g32*32 + 8*(reg>>2) + 4*half + (reg&3), col px = l31
#pragma unroll
    for (int a = 0; a < 2; ++a) {
        const int oc32 = (gb + a) * 32;
        if constexpr (!POOL) {
#pragma unroll
            for (int f = 0; f < 2; ++f) {
                int px = pxg * 64 + f * 32 + l31;
                int y  = px / W, xx = px - y * W;
#pragma unroll
                for (int g = 0; g < 4; ++g) {
                    int oc0 = oc32 + 8 * g + 4 * half;
                    float4 bv = *(const float4*)(bias + oc0);
                    floatx4 v;
#pragma unroll
                    for (int r = 0; r < 4; ++r) {
                        float t = acc[a][f][4 * g + r] + ((const float*)&bv)[r];
                        v[r] = t > 0.f ? t : 0.f;
                    }
                    long dst = ((((long)b * C8O + (oc0 >> 3)) * H + r0 + y) * W + xx) * 8 + (oc0 & 7);
                    store_bf4(act_out + dst, v);
                }
            }
        } else {
            constexpr int HO = H / 2, WO = W / 2;
#pragma unroll
            for (int g = 0; g < 4; ++g) {
                int oc0 = oc32 + 8 * g + 4 * half;
                float4 bv = *(const float4*)(bias + oc0);
                floatx4 rr[2];
#pragma unroll
                for (int f = 0; f < 2; ++f) {
                    floatx4 v;
#pragma unroll
                    for (int r = 0; r < 4; ++r) {
                        float t = acc[a][f][4 * g + r] + ((const float*)&bv)[r];
                        v[r] = t > 0.f ? t : 0.f;
                    }
                    rr[f] = max_xor(v, 1);            // x-pair
                }
                if constexpr (W == 32) {
                    floatx4 m = max4(rr[0], rr[1]);   // y-pair = frag pair
                    if ((lane & 1) == 0) {
                        int prow = r0 / 2 + pxg;
                        int pcol = l31 >> 1;
                        long dst = ((((long)b * C8O + (oc0 >> 3)) * HO + prow) * WO + pcol) * 8 + (oc0 & 7);
                        store_bf4(act_out + dst, m);
                    }
                } else if constexpr (W == 16) {
#pragma unroll
                    for (int f = 0; f < 2; ++f) {
                        floatx4 m = max_xor(rr[f], 16);   // y-pair: lane bit4
                        if ((lane & 1) == 0 && (lane & 16) == 0) {
                            int prow = r0 / 2 + pxg * 2 + f;
                            int pcol = (l31 & 15) >> 1;
                            long dst = ((((long)b * C8O + (oc0 >> 3)) * HO + prow) * WO + pcol) * 8 + (oc0 & 7);
                            store_bf4(act_out + dst, m);
                        }
                    }
                } else {  // W == 8, PXG == 1
#pragma unroll
                    for (int f = 0; f < 2; ++f) {
                        floatx4 m = max_xor(rr[f], 8);    // y-pair: lane bit3
                        if ((lane & 1) == 0 && (lane & 8) == 0) {
                            int prow = f * 2 + (l31 >> 4);
                            int pcol = (l31 & 7) >> 1;
                            long dst = ((((long)b * C8O + (oc0 >> 3)) * HO + prow) * WO + pcol) * 8 + (oc0 & 7);
                            store_bf4(act_out + dst, m);
                        }
                    }
                }
            }
        }
    }
}

// ---------------- classifier: wave per (b, class); feat [b][c8][y][x][8]
__global__ __launch_bounds__(256) void classifier_k(
    const ushort* __restrict__ feat, const int* __restrict__ tids,
    const float* __restrict__ cw, const float* __restrict__ cb,
    float* __restrict__ out, int B)
{
    int g = blockIdx.x * 256 + threadIdx.x;
    int wid = g >> 6, lane = g & 63;
    if (wid >= B * 5) return;
    int b = wid / 5, c = wid - b * 5;
    int t = tids[b];
    const float* wrow = cw + (long)(t * 5 + c) * 4096;
    const ushort* f = feat + (long)b * 4096;
    float s = 0.f;
#pragma unroll 4
    for (int d = lane; d < 4096; d += 64) {
        int fidx = (((d >> 7) * 16) + (d & 15)) * 8 + ((d >> 4) & 7);
        s += wrow[d] * bf2f(f[fidx]);
    }
#pragma unroll
    for (int off = 32; off > 0; off >>= 1) s += __shfl_down(s, off, 64);
    if (lane == 0) out[wid] = s + cb[t * 5 + c];
}

// ---------------------------------------------------------------------------
extern "C" void kernel_launch(void* const* d_in, const int* in_sizes, int n_in,
                              void* d_out, int out_size, void* d_ws, size_t ws_size,
                              hipStream_t stream)
{
    const float* x   = (const float*)d_in[0];
    const int*   tid = (const int*)d_in[1];
    const float* w0 = (const float*)d_in[2];  const float* b0 = (const float*)d_in[3];
    const float* w1 = (const float*)d_in[4];  const float* b1 = (const float*)d_in[5];
    const float* w2 = (const float*)d_in[6];  const float* b2 = (const float*)d_in[7];
    const float* w3 = (const float*)d_in[8];  const float* b3 = (const float*)d_in[9];
    const float* w4 = (const float*)d_in[10]; const float* b4 = (const float*)d_in[11];
    const float* w5 = (const float*)d_in[12]; const float* b5 = (const float*)d_in[13];
    const float* cw = (const float*)d_in[14];
    const float* cb = (const float*)d_in[15];
    float* outp = (float*)d_out;

    const int B = in_sizes[0] / (3 * 32 * 32);   // 512

    // ---- ws layout (halfword units) ----
    short* wt0  = (short*)d_ws;                   // 2048
    short* wts1 = wt0 + 2048;                     // 36864
    short* wts2 = wts1 + 36864;                   // 73728
    short* wts3 = wts2 + 73728;                   // 147456
    short* wts4 = wts3 + 147456;                  // 294912
    short* wts5 = wts4 + 294912;                  // 589824
    const size_t WT_HW = 2048 + 36864 + 73728 + 147456 + 294912 + 589824;
    const size_t fixed_bytes = WT_HW * 2;

    int Bc = B;
    while (Bc > 2 && fixed_bytes + (size_t)Bc * 2 * 65536 * 2 > ws_size) Bc >>= 1;
    if (Bc < 2) Bc = 2;

    ushort* bufA = (ushort*)((short*)d_ws + WT_HW);
    ushort* bufB = bufA + (size_t)Bc * 65536;

    wtransform_all<<<(int)((WT_HW + 255) / 256), 256, 0, stream>>>(
        w0, w1, w2, w3, w4, w5, wt0, wts1, wts2, wts3, wts4, wts5);

    for (int cb0 = 0; cb0 < B; cb0 += Bc) {
        const float* xc = x + (size_t)cb0 * 3 * 32 * 32;
        const int* tidc = tid + cb0;
        float* outc = outp + (size_t)cb0 * 5;

        // conv0: 3->64 @32x32 -> bufA [Bc][8][32][32][8]
        conv0_mfma<<<Bc * 2, 256, 0, stream>>>(xc, wt0, b0, bufA);
        // conv1+pool: 64->64 @32x32 (OCG=1, ROWS=8, NSTAGE=2) -> bufB 16x16
        conv32<64, 64, 32, 32, 8, 1, 2, true><<<Bc * 4, 256, 0, stream>>>(bufA, wts1, b1, bufB);
        // conv2: 64->128 @16x16 (OCG=2, ROWS=8, NSTAGE=1) -> bufA
        conv32<64, 128, 16, 16, 8, 2, 1, false><<<Bc * 2, 256, 0, stream>>>(bufB, wts2, b2, bufA);
        // conv3+pool: 128->128 @16x16 (OCG=2, ROWS=8, NSTAGE=2) -> bufB 8x8
        conv32<128, 128, 16, 16, 8, 2, 2, true><<<Bc * 2, 256, 0, stream>>>(bufA, wts3, b3, bufB);
        // conv4: 128->256 @8x8 (OCG=4, NSTAGE=1) -> bufA
        conv32<128, 256, 8, 8, 8, 4, 1, false><<<Bc, 256, 0, stream>>>(bufB, wts4, b4, bufA);
        // conv5+pool: 256->256 @8x8 (OCG=4, NSTAGE=2) -> bufB 4x4
        conv32<256, 256, 8, 8, 8, 4, 2, true><<<Bc, 256, 0, stream>>>(bufA, wts5, b5, bufB);
        // classifier
        classifier_k<<<(Bc * 5 * 64 + 255) / 256, 256, 0, stream>>>(bufB, tidc, cw, cb, outc, Bc);
    }
}